// Round 6
// baseline (560.610 us; speedup 1.0000x reference)
//
#include <hip/hip_runtime.h>
#include <hip/hip_fp16.h>
#include <cstdint>
#include <cstddef>

// DecompGrid R6: Morton-sorted gather with sorted point records.
//   1. transpose_all: grids (C,V)->(V,C) scaled fp16, 32 B/voxel  [1 kernel]
//   2. zero_hist; hist over 32768 Morton bins                     [2 kernels]
//   3. exclusive scan                                             [1 block]
//   4. scatter: rec[pos] = (x,y,z, bits(p))  (counting sort)      [1 kernel]
//   5. main: thread (sorted_pos, level); coalesced rec reads,
//      wave-local LDS out staging (no __syncthreads), NT stores   [1 kernel]

typedef float f32x4 __attribute__((ext_vector_type(4)));

#define GRID_SCALE 8192.0f
#define GRID_INV_SCALE (1.0f / 8192.0f)
#define NBINS 32768

__device__ __host__ constexpr int level_res(int l) {
    return l == 0 ? 16 : l == 1 ? 32 : l == 2 ? 64 : 128;
}

union F4H { f32x4 f; __half2 h[4]; };

// ---- 1. fused transpose + convert: (C=16,V) f32 -> (V,C=16) f16*SCALE ----
// total voxels = 4096 + 32768 + 262144 + 2097152 = 2,396,160
__global__ void transpose_all_kernel(const float* __restrict__ g0,
                                     const float* __restrict__ g1,
                                     const float* __restrict__ g2,
                                     const float* __restrict__ g3,
                                     __half* __restrict__ ws, int total) {
    for (int v = blockIdx.x * blockDim.x + threadIdx.x; v < total;
         v += gridDim.x * blockDim.x) {
        int vloc, nvox;
        const float* src;
        size_t doff;
        if (v < 4096) { vloc = v; nvox = 4096; src = g0; doff = 0; }
        else if (v < 36864) { vloc = v - 4096; nvox = 32768; src = g1; doff = 65536; }
        else if (v < 299008) { vloc = v - 36864; nvox = 262144; src = g2; doff = 589824; }
        else { vloc = v - 299008; nvox = 2097152; src = g3; doff = 4784128; }
        __half2 h[8];
#pragma unroll
        for (int c = 0; c < 8; ++c) {
            float a = src[(size_t)(2 * c) * nvox + vloc] * GRID_SCALE;
            float b = src[(size_t)(2 * c + 1) * nvox + vloc] * GRID_SCALE;
            h[c] = __floats2half2_rn(a, b);
        }
        union { __half2 h[4]; f32x4 f; } u0, u1;
#pragma unroll
        for (int j = 0; j < 4; ++j) { u0.h[j] = h[j]; u1.h[j] = h[4 + j]; }
        f32x4* o = reinterpret_cast<f32x4*>(ws + doff + (size_t)vloc * 16);
        o[0] = u0.f;
        o[1] = u1.f;
    }
}

// ---- sort helpers ----
__device__ inline uint32_t part1by2(uint32_t v) {
    v &= 0x3FF;
    v = (v | (v << 16)) & 0x030000FF;
    v = (v | (v << 8)) & 0x0300F00F;
    v = (v | (v << 4)) & 0x030C30C3;
    v = (v | (v << 2)) & 0x09249249;
    return v;
}

__device__ inline int morton_key(float cx, float cy, float cz) {
    int bx = min(max((int)floorf((cx + 1.0f) * 63.5f), 0), 126) >> 2;
    int by = min(max((int)floorf((cy + 1.0f) * 63.5f), 0), 126) >> 2;
    int bz = min(max((int)floorf((cz + 1.0f) * 63.5f), 0), 126) >> 2;
    return (int)(part1by2((uint32_t)bx) | (part1by2((uint32_t)by) << 1) |
                 (part1by2((uint32_t)bz) << 2));
}

__global__ void zero_hist_kernel(int* hist) {
    int i = blockIdx.x * blockDim.x + threadIdx.x;
    if (i < NBINS) hist[i] = 0;
}

__global__ void hist_kernel(const float* __restrict__ x, int* __restrict__ hist, int n) {
    int p = blockIdx.x * blockDim.x + threadIdx.x;
    if (p >= n) return;
    atomicAdd(&hist[morton_key(x[3 * (size_t)p], x[3 * (size_t)p + 1],
                               x[3 * (size_t)p + 2])], 1);
}

// ---- exclusive scan of 32768 bins, single block of 1024 ----
__global__ void __launch_bounds__(1024)
scan_kernel(const int* __restrict__ hist, int* __restrict__ offsets) {
    __shared__ int part[1024];
    const int t = threadIdx.x;
    const int base = t * (NBINS / 1024);
    int s = 0;
#pragma unroll
    for (int i = 0; i < NBINS / 1024; ++i) s += hist[base + i];
    part[t] = s;
    __syncthreads();
    for (int d = 1; d < 1024; d <<= 1) {
        int v = (t >= d) ? part[t - d] : 0;
        __syncthreads();
        part[t] += v;
        __syncthreads();
    }
    int run = part[t] - s;
#pragma unroll
    for (int i = 0; i < NBINS / 1024; ++i) {
        offsets[base + i] = run;
        run += hist[base + i];
    }
}

// ---- 4. scatter: counting sort into 16 B point records ----
__global__ void scatter_rec_kernel(const float* __restrict__ x, int* __restrict__ offsets,
                                   f32x4* __restrict__ rec, int n) {
    int p = blockIdx.x * blockDim.x + threadIdx.x;
    if (p >= n) return;
    const float cx = x[3 * (size_t)p], cy = x[3 * (size_t)p + 1],
                cz = x[3 * (size_t)p + 2];
    int pos = atomicAdd(&offsets[morton_key(cx, cy, cz)], 1);
    f32x4 r = {cx, cy, cz, __int_as_float(p)};
    __builtin_nontemporal_store(r, &rec[pos]);
}

// ---- 5. main: thread per (sorted_pos, level); wave-local staging ----
__global__ void __launch_bounds__(256)
decomp_main_kernel(const f32x4* __restrict__ rec, const __half* __restrict__ ws,
                   float* __restrict__ out, int n) {
    __shared__ float sacc[64 * 64];  // 64 points x 64 feats, 16 KB

    // XCD-chunked bijective swizzle: each XCD owns a contiguous sorted range.
    const int nwg = gridDim.x, b = blockIdx.x;
    const int q = nwg >> 3, r = nwg & 7;
    const int xcd = b & 7, idx = b >> 3;
    const int blk = (xcd < r ? xcd * (q + 1) : r * (q + 1) + (xcd - r) * q) + idx;

    const int wave = threadIdx.x >> 6;
    const int lane = threadIdx.x & 63;
    const int i = lane >> 2;  // point within wave (0..15)
    const int l = lane & 3;   // level
    const int wbase = blk * 64 + wave * 16;
    const int s = wbase + i;

    const f32x4 r4 = rec[min(s, n - 1)];
    const float cx = r4.x, cy = r4.y, cz = r4.z;

    const int R = 16 << l;
    // level base offset (halfs): 65536 * {0,1,9,73}[l]
    const int k_off = (int)((0x49090100u >> (8 * l)) & 0xFFu);
    const __half* __restrict__ g = ws + ((size_t)k_off << 16);

    const float fx = (cx + 1.0f) * 0.5f * (float)(R - 1);
    const float fy = (cy + 1.0f) * 0.5f * (float)(R - 1);
    const float fz = (cz + 1.0f) * 0.5f * (float)(R - 1);
    const int x0 = min(max((int)floorf(fx), 0), R - 2);
    const int y0 = min(max((int)floorf(fy), 0), R - 2);
    const int z0 = min(max((int)floorf(fz), 0), R - 2);

    const int base00 = (z0 * R + y0) * R + x0;
    const int rowoff[4] = {0, R, R * R, R * R + R};

    F4H u[4][4];
#pragma unroll
    for (int k = 0; k < 4; ++k) {
        const f32x4* qp =
            reinterpret_cast<const f32x4*>(g + (size_t)(base00 + rowoff[k]) * 16);
#pragma unroll
        for (int j = 0; j < 4; ++j) u[k][j].f = qp[j];
    }

    const float wx = fx - (float)x0;
    const float wy = fy - (float)y0;
    const float wz = fz - (float)z0;
    const float wzy[4] = {(1.0f - wz) * (1.0f - wy), (1.0f - wz) * wy,
                          wz * (1.0f - wy), wz * wy};

    float acc[16];
#pragma unroll
    for (int c = 0; c < 16; ++c) acc[c] = 0.0f;

#pragma unroll
    for (int k = 0; k < 4; ++k) {
        const float wA = wzy[k] * (1.0f - wx);
        const float wB = wzy[k] * wx;
#pragma unroll
        for (int j = 0; j < 4; ++j) {
            float2 a0 = __half22float2(u[k][0].h[j]);
            float2 b0 = __half22float2(u[k][2].h[j]);
            acc[2 * j + 0] += wA * a0.x + wB * b0.x;
            acc[2 * j + 1] += wA * a0.y + wB * b0.y;
            float2 a1 = __half22float2(u[k][1].h[j]);
            float2 b1 = __half22float2(u[k][3].h[j]);
            acc[8 + 2 * j + 0] += wA * a1.x + wB * b1.x;
            acc[8 + 2 * j + 1] += wA * a1.y + wB * b1.y;
        }
    }

    // Wave-local LDS staging, XOR-swizzled columns (row = point, 64 floats).
    // Write:  float-idx (l*16 + j*4) ^ ((i&7)<<3)  within the row.
    const int row = wave * 16 + i;
    float* srow = &sacc[row * 64];
#pragma unroll
    for (int j = 0; j < 4; ++j) {
        f32x4 v = {acc[4 * j + 0] * GRID_INV_SCALE, acc[4 * j + 1] * GRID_INV_SCALE,
                   acc[4 * j + 2] * GRID_INV_SCALE, acc[4 * j + 3] * GRID_INV_SCALE};
        *reinterpret_cast<f32x4*>(&srow[((l * 16 + j * 4) ^ ((i & 7) << 3))]) = v;
    }
    __builtin_amdgcn_wave_barrier();  // wave-lockstep: no __syncthreads needed

    // Redistribute within the wave: 4 iters x (4 points x 16 lanes x 16 B)
    // -> each point's 256 B written as full lines, NT.
#pragma unroll
    for (int it = 0; it < 4; ++it) {
        const int i2 = it * 4 + (lane >> 4);
        const int s2 = wbase + i2;
        if (s2 < n) {
            const f32x4 rr = rec[s2];
            const int p = __float_as_int(rr.w);
            const int c4 = lane & 15;
            const int row2 = wave * 16 + i2;
            f32x4 v = *reinterpret_cast<const f32x4*>(
                &sacc[row2 * 64 + ((c4 * 4) ^ ((i2 & 7) << 3))]);
            __builtin_nontemporal_store(
                v, reinterpret_cast<f32x4*>(out + (size_t)p * 64 + c4 * 4));
        }
    }
}

// ---- fallback (no ws): direct strided f32 gather, slow but correct ----
__global__ void __launch_bounds__(256)
decomp_direct_kernel(const float* __restrict__ x, const float* __restrict__ g0,
                     const float* __restrict__ g1, const float* __restrict__ g2,
                     const float* __restrict__ g3, float* __restrict__ out, int n) {
    int p = blockIdx.x * blockDim.x + threadIdx.x;
    if (p >= n) return;
    const float cx = x[3 * (size_t)p], cy = x[3 * (size_t)p + 1], cz = x[3 * (size_t)p + 2];
    const float* grids[4] = {g0, g1, g2, g3};
#pragma unroll
    for (int l = 0; l < 4; ++l) {
        const int R = level_res(l);
        const float* g = grids[l];
        float fx = (cx + 1.0f) * 0.5f * (R - 1), fy = (cy + 1.0f) * 0.5f * (R - 1),
              fz = (cz + 1.0f) * 0.5f * (R - 1);
        int x0 = min(max((int)floorf(fx), 0), R - 2);
        int y0 = min(max((int)floorf(fy), 0), R - 2);
        int z0 = min(max((int)floorf(fz), 0), R - 2);
        float wx = fx - x0, wy = fy - y0, wz = fz - z0;
        const size_t V = (size_t)R * R * R;
        const int base = (z0 * R + y0) * R + x0;
        const int ro[4] = {0, R, R * R, R * R + R};
        const float wzy[4] = {(1 - wz) * (1 - wy), (1 - wz) * wy, wz * (1 - wy), wz * wy};
        for (int c = 0; c < 16; ++c) {
            float a = 0.f;
            for (int k = 0; k < 4; ++k) {
                const float* gc = g + (size_t)c * V + base + ro[k];
                a += wzy[k] * ((1 - wx) * gc[0] + wx * gc[1]);
            }
            out[(size_t)p * 64 + l * 16 + c] = a;
        }
    }
}

extern "C" void kernel_launch(void* const* d_in, const int* in_sizes, int n_in,
                              void* d_out, int out_size, void* d_ws, size_t ws_size,
                              hipStream_t stream) {
    const float* x = (const float*)d_in[0];
    const float* g[4] = {(const float*)d_in[1], (const float*)d_in[2],
                         (const float*)d_in[3], (const float*)d_in[4]};
    float* out = (float*)d_out;
    const int n = in_sizes[0] / 3;

    // ws layout: [grids fp16 76,677,120 B][rec f32x4 16n B][hist 128KB][offs 128KB]
    size_t grid_halfs = 0;
    for (int l = 0; l < 4; ++l) {
        size_t R = (size_t)level_res(l);
        grid_halfs += R * R * R * 16;
    }
    const size_t grid_bytes = grid_halfs * sizeof(__half);  // 16-B aligned
    const size_t rec_off = grid_bytes;
    const size_t hist_off = rec_off + (size_t)n * 16;
    const size_t offs_off = hist_off + (size_t)NBINS * 4;
    const size_t needed = offs_off + (size_t)NBINS * 4;

    const int block = 256;
    if (ws_size < needed) {
        int grid = (n + block - 1) / block;
        decomp_direct_kernel<<<grid, block, 0, stream>>>(x, g[0], g[1], g[2], g[3], out, n);
        return;
    }

    char* wsb = (char*)d_ws;
    __half* wsh = (__half*)d_ws;
    f32x4* rec = (f32x4*)(wsb + rec_off);
    int* hist = (int*)(wsb + hist_off);
    int* offs = (int*)(wsb + offs_off);

    const int total_vox = 4096 + 32768 + 262144 + 2097152;
    transpose_all_kernel<<<(total_vox + block - 1) / block, block, 0, stream>>>(
        g[0], g[1], g[2], g[3], wsh, total_vox);

    zero_hist_kernel<<<(NBINS + block - 1) / block, block, 0, stream>>>(hist);
    int pgrid = (n + block - 1) / block;
    hist_kernel<<<pgrid, block, 0, stream>>>(x, hist, n);
    scan_kernel<<<1, 1024, 0, stream>>>(hist, offs);
    scatter_rec_kernel<<<pgrid, block, 0, stream>>>(x, offs, rec, n);

    int mgrid = (n + 63) / 64;  // 64 points per block
    decomp_main_kernel<<<mgrid, block, 0, stream>>>(rec, wsh, out, n);
}

// Round 7
// 470.132 us; speedup vs baseline: 1.1925x; 1.1925x over previous
//
#include <hip/hip_runtime.h>
#include <hip/hip_fp16.h>
#include <cstdint>
#include <cstddef>

// DecompGrid R7: Morton-sorted, block-per-region gather with LDS level-3 tile.
//   1. transpose_all: grids (C,V)->(V,C) scaled fp16, 32 B/voxel  [1 kernel]
//   2. zero_hist; hist over 32768 Morton bins                     [2 kernels]
//   3. exclusive scan -> offsets (working) + bin_start (kept)     [1 block]
//   4. scatter: rec[pos] = (x,y,z, bits(p))  (counting sort)      [1 kernel]
//   5. main: block per 2x2x2-bin region (4096 blocks, ~488 pts).
//      Level-3 region tile (9^3 vox x 32 B = 23 KB) cooperatively
//      loaded to LDS; L3 gathers via ds_read_b128. Levels 0-2 via
//      global (L1-resident). Wave-local out staging, NT stores.

typedef float f32x4 __attribute__((ext_vector_type(4)));

#define GRID_SCALE 8192.0f
#define GRID_INV_SCALE (1.0f / 8192.0f)
#define NBINS 32768
#define NREG 4096

__device__ __host__ constexpr int level_res(int l) {
    return l == 0 ? 16 : l == 1 ? 32 : l == 2 ? 64 : 128;
}

union F4H { f32x4 f; __half2 h[4]; };

// ---- 1. fused transpose + convert: (C=16,V) f32 -> (V,C=16) f16*SCALE ----
__global__ void transpose_all_kernel(const float* __restrict__ g0,
                                     const float* __restrict__ g1,
                                     const float* __restrict__ g2,
                                     const float* __restrict__ g3,
                                     __half* __restrict__ ws, int total) {
    for (int v = blockIdx.x * blockDim.x + threadIdx.x; v < total;
         v += gridDim.x * blockDim.x) {
        int vloc, nvox;
        const float* src;
        size_t doff;
        if (v < 4096) { vloc = v; nvox = 4096; src = g0; doff = 0; }
        else if (v < 36864) { vloc = v - 4096; nvox = 32768; src = g1; doff = 65536; }
        else if (v < 299008) { vloc = v - 36864; nvox = 262144; src = g2; doff = 589824; }
        else { vloc = v - 299008; nvox = 2097152; src = g3; doff = 4784128; }
        __half2 h[8];
#pragma unroll
        for (int c = 0; c < 8; ++c) {
            float a = src[(size_t)(2 * c) * nvox + vloc] * GRID_SCALE;
            float b = src[(size_t)(2 * c + 1) * nvox + vloc] * GRID_SCALE;
            h[c] = __floats2half2_rn(a, b);
        }
        union { __half2 h[4]; f32x4 f; } u0, u1;
#pragma unroll
        for (int j = 0; j < 4; ++j) { u0.h[j] = h[j]; u1.h[j] = h[4 + j]; }
        f32x4* o = reinterpret_cast<f32x4*>(ws + doff + (size_t)vloc * 16);
        o[0] = u0.f;
        o[1] = u1.f;
    }
}

// ---- morton helpers ----
__device__ inline uint32_t part1by2(uint32_t v) {
    v &= 0x3FF;
    v = (v | (v << 16)) & 0x030000FF;
    v = (v | (v << 8)) & 0x0300F00F;
    v = (v | (v << 4)) & 0x030C30C3;
    v = (v | (v << 2)) & 0x09249249;
    return v;
}

__device__ inline uint32_t compact1by2(uint32_t v) {
    v &= 0x09249249;
    v = (v | (v >> 2)) & 0x030C30C3;
    v = (v | (v >> 4)) & 0x0300F00F;
    v = (v | (v >> 8)) & 0x030000FF;
    v = (v | (v >> 16)) & 0x3FF;
    return v;
}

__device__ inline int morton_key(float cx, float cy, float cz) {
    int bx = min(max((int)floorf((cx + 1.0f) * 63.5f), 0), 126) >> 2;
    int by = min(max((int)floorf((cy + 1.0f) * 63.5f), 0), 126) >> 2;
    int bz = min(max((int)floorf((cz + 1.0f) * 63.5f), 0), 126) >> 2;
    return (int)(part1by2((uint32_t)bx) | (part1by2((uint32_t)by) << 1) |
                 (part1by2((uint32_t)bz) << 2));
}

__global__ void zero_hist_kernel(int* hist) {
    int i = blockIdx.x * blockDim.x + threadIdx.x;
    if (i < NBINS) hist[i] = 0;
}

__global__ void hist_kernel(const float* __restrict__ x, int* __restrict__ hist, int n) {
    int p = blockIdx.x * blockDim.x + threadIdx.x;
    if (p >= n) return;
    atomicAdd(&hist[morton_key(x[3 * (size_t)p], x[3 * (size_t)p + 1],
                               x[3 * (size_t)p + 2])], 1);
}

// ---- 3. exclusive scan of 32768 bins; keep a pristine copy in bin_start ----
__global__ void __launch_bounds__(1024)
scan_kernel(const int* __restrict__ hist, int* __restrict__ offsets,
            int* __restrict__ bin_start) {
    __shared__ int part[1024];
    const int t = threadIdx.x;
    const int base = t * (NBINS / 1024);
    int s = 0;
#pragma unroll
    for (int i = 0; i < NBINS / 1024; ++i) s += hist[base + i];
    part[t] = s;
    __syncthreads();
    for (int d = 1; d < 1024; d <<= 1) {
        int v = (t >= d) ? part[t - d] : 0;
        __syncthreads();
        part[t] += v;
        __syncthreads();
    }
    int run = part[t] - s;
#pragma unroll
    for (int i = 0; i < NBINS / 1024; ++i) {
        offsets[base + i] = run;
        bin_start[base + i] = run;
        run += hist[base + i];
    }
    if (t == 1023) bin_start[NBINS] = run;  // == n
}

// ---- 4. scatter: counting sort into 16 B point records ----
__global__ void scatter_rec_kernel(const float* __restrict__ x, int* __restrict__ offsets,
                                   f32x4* __restrict__ rec, int n) {
    int p = blockIdx.x * blockDim.x + threadIdx.x;
    if (p >= n) return;
    const float cx = x[3 * (size_t)p], cy = x[3 * (size_t)p + 1],
                cz = x[3 * (size_t)p + 2];
    int pos = atomicAdd(&offsets[morton_key(cx, cy, cz)], 1);
    f32x4 r = {cx, cy, cz, __int_as_float(p)};
    rec[pos] = r;
}

// ---- 5. main: block per region ----
__global__ void __launch_bounds__(256)
decomp_region_kernel(const f32x4* __restrict__ rec, const __half* __restrict__ ws,
                     const int* __restrict__ bin_start, float* __restrict__ out) {
    __shared__ alignas(16) __half tile[9 * 9 * 9 * 16];  // 23,328 B
    __shared__ alignas(16) float sacc[64 * 64];          // 16 KB
    __shared__ int sp[64];

    // XCD swizzle over 4096 regions (4096 % 8 == 0): each XCD gets a
    // morton-contiguous (spatially compact) chunk of 512 regions.
    const int b = blockIdx.x;
    const int reg = (b & 7) * (NREG / 8) + (b >> 3);

    const int start = bin_start[reg * 8];
    const int end = bin_start[reg * 8 + 8];
    const int count = end - start;
    if (count <= 0) return;

    // region coords (0..15 each); level-3 corner base = 8*r
    const int rx = (int)compact1by2((uint32_t)reg);
    const int ry = (int)compact1by2((uint32_t)reg >> 1);
    const int rz = (int)compact1by2((uint32_t)reg >> 2);
    const int CX = rx * 8, CY = ry * 8, CZ = rz * 8;

    // cooperative level-3 tile load: 9^3 voxels x 32 B
    const __half* __restrict__ g3 = ws + ((size_t)73 << 16);
    for (int v = threadIdx.x; v < 729; v += 256) {
        const int tz = v / 81, rem = v - tz * 81, ty = rem / 9, tx = rem - ty * 9;
        const int gz = min(CZ + tz, 127), gy = min(CY + ty, 127), gx = min(CX + tx, 127);
        const f32x4* src = reinterpret_cast<const f32x4*>(
            g3 + (size_t)((gz * 128 + gy) * 128 + gx) * 16);
        f32x4* dst = reinterpret_cast<f32x4*>(&tile[(size_t)v * 16]);
        dst[0] = src[0];
        dst[1] = src[1];
    }
    __syncthreads();

    const int wave = threadIdx.x >> 6;
    const int lane = threadIdx.x & 63;
    const int i = lane >> 2;  // point slot within wave (0..15)
    const int l = lane & 3;   // level
    const int row = wave * 16 + i;

    const int iters = (count + 63) >> 6;
    for (int it = 0; it < iters; ++it) {
        const int ibase = it * 64 + wave * 16;
        const int s = start + ibase + i;
        const f32x4 r4 = rec[min(s, end - 1)];
        const float cx = r4.x, cy = r4.y, cz = r4.z;

        const int R = 16 << l;
        const float fx = (cx + 1.0f) * 0.5f * (float)(R - 1);
        const float fy = (cy + 1.0f) * 0.5f * (float)(R - 1);
        const float fz = (cz + 1.0f) * 0.5f * (float)(R - 1);
        const int x0 = min(max((int)floorf(fx), 0), R - 2);
        const int y0 = min(max((int)floorf(fy), 0), R - 2);
        const int z0 = min(max((int)floorf(fz), 0), R - 2);

        F4H u[4][4];
        if (l == 3) {
            // guaranteed in-tile: x0 in [CX, CX+7] for this region's points
            const int lvox = ((z0 - CZ) * 9 + (y0 - CY)) * 9 + (x0 - CX);
            const int loff[4] = {0, 9, 81, 90};
#pragma unroll
            for (int k = 0; k < 4; ++k) {
                const f32x4* qp =
                    reinterpret_cast<const f32x4*>(&tile[(size_t)(lvox + loff[k]) * 16]);
#pragma unroll
                for (int j = 0; j < 4; ++j) u[k][j].f = qp[j];
            }
        } else {
            // level base offset (halfs): 65536 * {0,1,9}[l]
            const int k_off = (int)((0x090100u >> (8 * l)) & 0xFFu);
            const __half* __restrict__ g = ws + ((size_t)k_off << 16);
            const int base00 = (z0 * R + y0) * R + x0;
            const int rowoff[4] = {0, R, R * R, R * R + R};
#pragma unroll
            for (int k = 0; k < 4; ++k) {
                const f32x4* qp = reinterpret_cast<const f32x4*>(
                    g + (size_t)(base00 + rowoff[k]) * 16);
#pragma unroll
                for (int j = 0; j < 4; ++j) u[k][j].f = qp[j];
            }
        }

        const float wx = fx - (float)x0;
        const float wy = fy - (float)y0;
        const float wz = fz - (float)z0;
        const float wzy[4] = {(1.0f - wz) * (1.0f - wy), (1.0f - wz) * wy,
                              wz * (1.0f - wy), wz * wy};

        float acc[16];
#pragma unroll
        for (int c = 0; c < 16; ++c) acc[c] = 0.0f;

#pragma unroll
        for (int k = 0; k < 4; ++k) {
            const float wA = wzy[k] * (1.0f - wx);
            const float wB = wzy[k] * wx;
#pragma unroll
            for (int j = 0; j < 4; ++j) {
                float2 a0 = __half22float2(u[k][0].h[j]);
                float2 b0 = __half22float2(u[k][2].h[j]);
                acc[2 * j + 0] += wA * a0.x + wB * b0.x;
                acc[2 * j + 1] += wA * a0.y + wB * b0.y;
                float2 a1 = __half22float2(u[k][1].h[j]);
                float2 b1 = __half22float2(u[k][3].h[j]);
                acc[8 + 2 * j + 0] += wA * a1.x + wB * b1.x;
                acc[8 + 2 * j + 1] += wA * a1.y + wB * b1.y;
            }
        }

        // wave-local LDS staging with XOR-swizzled columns
        float* srow = &sacc[row * 64];
#pragma unroll
        for (int j = 0; j < 4; ++j) {
            f32x4 v = {acc[4 * j + 0] * GRID_INV_SCALE, acc[4 * j + 1] * GRID_INV_SCALE,
                       acc[4 * j + 2] * GRID_INV_SCALE, acc[4 * j + 3] * GRID_INV_SCALE};
            *reinterpret_cast<f32x4*>(&srow[((l * 16 + j * 4) ^ ((i & 7) << 3))]) = v;
        }
        if (l == 0) sp[row] = __float_as_int(r4.w);
        __builtin_amdgcn_wave_barrier();

        // redistribute within the wave: each point's 256 B as full lines, NT
#pragma unroll
        for (int gq = 0; gq < 4; ++gq) {
            const int i2 = gq * 4 + (lane >> 4);
            const int s2 = start + ibase + i2;
            if (s2 < end) {
                const int row2 = wave * 16 + i2;
                const int p = sp[row2];
                const int c4 = lane & 15;
                f32x4 v = *reinterpret_cast<const f32x4*>(
                    &sacc[row2 * 64 + ((c4 * 4) ^ ((i2 & 7) << 3))]);
                __builtin_nontemporal_store(
                    v, reinterpret_cast<f32x4*>(out + (size_t)p * 64 + c4 * 4));
            }
        }
        __builtin_amdgcn_wave_barrier();
    }
}

// ---- fallback (no ws): direct strided f32 gather, slow but correct ----
__global__ void __launch_bounds__(256)
decomp_direct_kernel(const float* __restrict__ x, const float* __restrict__ g0,
                     const float* __restrict__ g1, const float* __restrict__ g2,
                     const float* __restrict__ g3, float* __restrict__ out, int n) {
    int p = blockIdx.x * blockDim.x + threadIdx.x;
    if (p >= n) return;
    const float cx = x[3 * (size_t)p], cy = x[3 * (size_t)p + 1], cz = x[3 * (size_t)p + 2];
    const float* grids[4] = {g0, g1, g2, g3};
#pragma unroll
    for (int l = 0; l < 4; ++l) {
        const int R = level_res(l);
        const float* g = grids[l];
        float fx = (cx + 1.0f) * 0.5f * (R - 1), fy = (cy + 1.0f) * 0.5f * (R - 1),
              fz = (cz + 1.0f) * 0.5f * (R - 1);
        int x0 = min(max((int)floorf(fx), 0), R - 2);
        int y0 = min(max((int)floorf(fy), 0), R - 2);
        int z0 = min(max((int)floorf(fz), 0), R - 2);
        float wx = fx - x0, wy = fy - y0, wz = fz - z0;
        const size_t V = (size_t)R * R * R;
        const int base = (z0 * R + y0) * R + x0;
        const int ro[4] = {0, R, R * R, R * R + R};
        const float wzy[4] = {(1 - wz) * (1 - wy), (1 - wz) * wy, wz * (1 - wy), wz * wy};
        for (int c = 0; c < 16; ++c) {
            float a = 0.f;
            for (int k = 0; k < 4; ++k) {
                const float* gc = g + (size_t)c * V + base + ro[k];
                a += wzy[k] * ((1 - wx) * gc[0] + wx * gc[1]);
            }
            out[(size_t)p * 64 + l * 16 + c] = a;
        }
    }
}

extern "C" void kernel_launch(void* const* d_in, const int* in_sizes, int n_in,
                              void* d_out, int out_size, void* d_ws, size_t ws_size,
                              hipStream_t stream) {
    const float* x = (const float*)d_in[0];
    const float* g[4] = {(const float*)d_in[1], (const float*)d_in[2],
                         (const float*)d_in[3], (const float*)d_in[4]};
    float* out = (float*)d_out;
    const int n = in_sizes[0] / 3;

    // ws layout: [grids fp16 76,677,120 B][rec 16n][hist][offs][bin_start]
    size_t grid_halfs = 0;
    for (int l = 0; l < 4; ++l) {
        size_t R = (size_t)level_res(l);
        grid_halfs += R * R * R * 16;
    }
    const size_t grid_bytes = grid_halfs * sizeof(__half);
    const size_t rec_off = grid_bytes;
    const size_t hist_off = rec_off + (size_t)n * 16;
    const size_t offs_off = hist_off + (size_t)NBINS * 4;
    const size_t bstart_off = offs_off + (size_t)NBINS * 4;
    const size_t needed = bstart_off + (size_t)(NBINS + 1) * 4;

    const int block = 256;
    if (ws_size < needed) {
        int grid = (n + block - 1) / block;
        decomp_direct_kernel<<<grid, block, 0, stream>>>(x, g[0], g[1], g[2], g[3], out, n);
        return;
    }

    char* wsb = (char*)d_ws;
    __half* wsh = (__half*)d_ws;
    f32x4* rec = (f32x4*)(wsb + rec_off);
    int* hist = (int*)(wsb + hist_off);
    int* offs = (int*)(wsb + offs_off);
    int* bstart = (int*)(wsb + bstart_off);

    const int total_vox = 4096 + 32768 + 262144 + 2097152;
    transpose_all_kernel<<<(total_vox + block - 1) / block, block, 0, stream>>>(
        g[0], g[1], g[2], g[3], wsh, total_vox);

    zero_hist_kernel<<<(NBINS + block - 1) / block, block, 0, stream>>>(hist);
    int pgrid = (n + block - 1) / block;
    hist_kernel<<<pgrid, block, 0, stream>>>(x, hist, n);
    scan_kernel<<<1, 1024, 0, stream>>>(hist, offs, bstart);
    scatter_rec_kernel<<<pgrid, block, 0, stream>>>(x, offs, rec, n);

    decomp_region_kernel<<<NREG, block, 0, stream>>>(rec, wsh, bstart, out);
}

// Round 8
// 433.298 us; speedup vs baseline: 1.2938x; 1.0850x over previous
//
#include <hip/hip_runtime.h>
#include <hip/hip_fp16.h>
#include <cstdint>
#include <cstddef>

// DecompGrid R8: Morton-sorted, block-per-region, ALL levels LDS-tiled,
// wave-per-level specialization (wave w handles level w, lane = point).
//   1. transpose_all: grids (C,V)->(V,C) scaled fp16, 32 B/voxel  [1 kernel]
//   2. hipMemsetAsync hist; hist over 32768 Morton bins           [1 kernel]
//   3. exclusive scan -> offsets (working) + bin_start (kept)     [1 block]
//   4. scatter: rec[pos] = (x,y,z, bits(p))  (counting sort)      [1 kernel]
//   5. main: block per 2x2x2-bin region (4096 blocks, ~488 pts).
//      4 level tiles (3^3+4^3+6^3+9^3 = 1036 vox x 32 B = 33 KB)
//      cooperatively loaded; every gather is ds_read_b128.
//      Block-wide LDS out staging (XOR swizzle), full-line NT stores.

typedef float f32x4 __attribute__((ext_vector_type(4)));

#define GRID_SCALE 8192.0f
#define GRID_INV_SCALE (1.0f / 8192.0f)
#define NBINS 32768
#define NREG 4096

__device__ __host__ constexpr int level_res(int l) {
    return l == 0 ? 16 : l == 1 ? 32 : l == 2 ? 64 : 128;
}

union F4H { f32x4 f; __half2 h[4]; };

// tile geometry: dims {3,4,6,9}, voxel offsets {0,27,91,307}, total 1036
template <int L> struct TileC {
    static constexpr int R = 16 << L;
    static constexpr int TD = (L == 0 ? 3 : L == 1 ? 4 : L == 2 ? 6 : 9);
    static constexpr int TOFF = (L == 0 ? 0 : L == 1 ? 27 : L == 2 ? 91 : 307);
    // level base offset in ws (halfs)
    static constexpr size_t LOFF =
        (L == 0 ? 0u : L == 1 ? 65536u : L == 2 ? 589824u : 4784128u);
};

// ---- 1. fused transpose + convert ----
__global__ void transpose_all_kernel(const float* __restrict__ g0,
                                     const float* __restrict__ g1,
                                     const float* __restrict__ g2,
                                     const float* __restrict__ g3,
                                     __half* __restrict__ ws, int total) {
    for (int v = blockIdx.x * blockDim.x + threadIdx.x; v < total;
         v += gridDim.x * blockDim.x) {
        int vloc, nvox;
        const float* src;
        size_t doff;
        if (v < 4096) { vloc = v; nvox = 4096; src = g0; doff = 0; }
        else if (v < 36864) { vloc = v - 4096; nvox = 32768; src = g1; doff = 65536; }
        else if (v < 299008) { vloc = v - 36864; nvox = 262144; src = g2; doff = 589824; }
        else { vloc = v - 299008; nvox = 2097152; src = g3; doff = 4784128; }
        __half2 h[8];
#pragma unroll
        for (int c = 0; c < 8; ++c) {
            float a = src[(size_t)(2 * c) * nvox + vloc] * GRID_SCALE;
            float b = src[(size_t)(2 * c + 1) * nvox + vloc] * GRID_SCALE;
            h[c] = __floats2half2_rn(a, b);
        }
        union { __half2 h[4]; f32x4 f; } u0, u1;
#pragma unroll
        for (int j = 0; j < 4; ++j) { u0.h[j] = h[j]; u1.h[j] = h[4 + j]; }
        f32x4* o = reinterpret_cast<f32x4*>(ws + doff + (size_t)vloc * 16);
        o[0] = u0.f;
        o[1] = u1.f;
    }
}

// ---- morton helpers ----
__device__ inline uint32_t part1by2(uint32_t v) {
    v &= 0x3FF;
    v = (v | (v << 16)) & 0x030000FF;
    v = (v | (v << 8)) & 0x0300F00F;
    v = (v | (v << 4)) & 0x030C30C3;
    v = (v | (v << 2)) & 0x09249249;
    return v;
}

__device__ inline uint32_t compact1by2(uint32_t v) {
    v &= 0x09249249;
    v = (v | (v >> 2)) & 0x030C30C3;
    v = (v | (v >> 4)) & 0x0300F00F;
    v = (v | (v >> 8)) & 0x030000FF;
    v = (v | (v >> 16)) & 0x3FF;
    return v;
}

__device__ inline int morton_key(float cx, float cy, float cz) {
    int bx = min(max((int)floorf((cx + 1.0f) * 63.5f), 0), 126) >> 2;
    int by = min(max((int)floorf((cy + 1.0f) * 63.5f), 0), 126) >> 2;
    int bz = min(max((int)floorf((cz + 1.0f) * 63.5f), 0), 126) >> 2;
    return (int)(part1by2((uint32_t)bx) | (part1by2((uint32_t)by) << 1) |
                 (part1by2((uint32_t)bz) << 2));
}

__global__ void hist_kernel(const float* __restrict__ x, int* __restrict__ hist, int n) {
    int p = blockIdx.x * blockDim.x + threadIdx.x;
    if (p >= n) return;
    atomicAdd(&hist[morton_key(x[3 * (size_t)p], x[3 * (size_t)p + 1],
                               x[3 * (size_t)p + 2])], 1);
}

// ---- 3. exclusive scan; keep pristine copy in bin_start ----
__global__ void __launch_bounds__(1024)
scan_kernel(const int* __restrict__ hist, int* __restrict__ offsets,
            int* __restrict__ bin_start) {
    __shared__ int part[1024];
    const int t = threadIdx.x;
    const int base = t * (NBINS / 1024);
    int s = 0;
#pragma unroll
    for (int i = 0; i < NBINS / 1024; ++i) s += hist[base + i];
    part[t] = s;
    __syncthreads();
    for (int d = 1; d < 1024; d <<= 1) {
        int v = (t >= d) ? part[t - d] : 0;
        __syncthreads();
        part[t] += v;
        __syncthreads();
    }
    int run = part[t] - s;
#pragma unroll
    for (int i = 0; i < NBINS / 1024; ++i) {
        offsets[base + i] = run;
        bin_start[base + i] = run;
        run += hist[base + i];
    }
    if (t == 1023) bin_start[NBINS] = run;  // == n
}

// ---- 4. scatter: counting sort into 16 B point records ----
__global__ void scatter_rec_kernel(const float* __restrict__ x, int* __restrict__ offsets,
                                   f32x4* __restrict__ rec, int n) {
    int p = blockIdx.x * blockDim.x + threadIdx.x;
    if (p >= n) return;
    const float cx = x[3 * (size_t)p], cy = x[3 * (size_t)p + 1],
                cz = x[3 * (size_t)p + 2];
    int pos = atomicAdd(&offsets[morton_key(cx, cy, cz)], 1);
    f32x4 r = {cx, cy, cz, __int_as_float(p)};
    rec[pos] = r;
}

// ---- tile loader for level L ----
template <int L>
__device__ inline void load_tile(const __half* __restrict__ ws, __half* tile,
                                 int rx, int ry, int rz, int tid) {
    using C = TileC<L>;
    constexpr int TD = C::TD, R = C::R;
    const int BX = (L == 3) ? (rx << 3) : max((rx << L) - 1, 0);
    const int BY = (L == 3) ? (ry << 3) : max((ry << L) - 1, 0);
    const int BZ = (L == 3) ? (rz << 3) : max((rz << L) - 1, 0);
    const __half* __restrict__ g = ws + C::LOFF;
    for (int v = tid; v < TD * TD * TD; v += 256) {
        const int tz = v / (TD * TD), rem = v - tz * TD * TD;
        const int ty = rem / TD, tx = rem - ty * TD;
        const int gz = min(BZ + tz, R - 1), gy = min(BY + ty, R - 1),
                  gx = min(BX + tx, R - 1);
        const f32x4* src =
            reinterpret_cast<const f32x4*>(g + (size_t)((gz * R + gy) * R + gx) * 16);
        f32x4* dst = reinterpret_cast<f32x4*>(&tile[(size_t)(C::TOFF + v) * 16]);
        dst[0] = src[0];
        dst[1] = src[1];
    }
}

// ---- per-level gather + lerp from LDS tile ----
template <int L>
__device__ inline void gather_level(const __half* tile, int rx, int ry, int rz,
                                    float cx, float cy, float cz, float* acc) {
    using C = TileC<L>;
    constexpr int TD = C::TD, R = C::R;
    const int BX = (L == 3) ? (rx << 3) : max((rx << L) - 1, 0);
    const int BY = (L == 3) ? (ry << 3) : max((ry << L) - 1, 0);
    const int BZ = (L == 3) ? (rz << 3) : max((rz << L) - 1, 0);

    const float fx = (cx + 1.0f) * 0.5f * (float)(R - 1);
    const float fy = (cy + 1.0f) * 0.5f * (float)(R - 1);
    const float fz = (cz + 1.0f) * 0.5f * (float)(R - 1);
    const int x0 = min(max((int)floorf(fx), 0), R - 2);
    const int y0 = min(max((int)floorf(fy), 0), R - 2);
    const int z0 = min(max((int)floorf(fz), 0), R - 2);

    const int lvox = C::TOFF + ((z0 - BZ) * TD + (y0 - BY)) * TD + (x0 - BX);
    constexpr int loff0 = 0, loff1 = TD, loff2 = TD * TD, loff3 = TD * TD + TD;
    const int loffs[4] = {loff0, loff1, loff2, loff3};

    F4H u[4][4];
#pragma unroll
    for (int k = 0; k < 4; ++k) {
        const f32x4* qp =
            reinterpret_cast<const f32x4*>(&tile[(size_t)(lvox + loffs[k]) * 16]);
#pragma unroll
        for (int j = 0; j < 4; ++j) u[k][j].f = qp[j];
    }

    const float wx = fx - (float)x0;
    const float wy = fy - (float)y0;
    const float wz = fz - (float)z0;
    const float wzy[4] = {(1.0f - wz) * (1.0f - wy), (1.0f - wz) * wy,
                          wz * (1.0f - wy), wz * wy};

#pragma unroll
    for (int c = 0; c < 16; ++c) acc[c] = 0.0f;
#pragma unroll
    for (int k = 0; k < 4; ++k) {
        const float wA = wzy[k] * (1.0f - wx);
        const float wB = wzy[k] * wx;
#pragma unroll
        for (int j = 0; j < 4; ++j) {
            float2 a0 = __half22float2(u[k][0].h[j]);
            float2 b0 = __half22float2(u[k][2].h[j]);
            acc[2 * j + 0] += wA * a0.x + wB * b0.x;
            acc[2 * j + 1] += wA * a0.y + wB * b0.y;
            float2 a1 = __half22float2(u[k][1].h[j]);
            float2 b1 = __half22float2(u[k][3].h[j]);
            acc[8 + 2 * j + 0] += wA * a1.x + wB * b1.x;
            acc[8 + 2 * j + 1] += wA * a1.y + wB * b1.y;
        }
    }
}

// ---- 5. main: block per region, wave-per-level ----
__global__ void __launch_bounds__(256)
decomp_region_kernel(const f32x4* __restrict__ rec, const __half* __restrict__ ws,
                     const int* __restrict__ bin_start, float* __restrict__ out) {
    __shared__ alignas(16) __half tile[1036 * 16];  // 33,152 B
    __shared__ alignas(16) float sacc[64 * 64];     // 16 KB
    __shared__ int sp[64];

    // XCD swizzle over 4096 regions (4096 % 8 == 0)
    const int b = blockIdx.x;
    const int reg = (b & 7) * (NREG / 8) + (b >> 3);

    const int start = bin_start[reg * 8];
    const int end = bin_start[reg * 8 + 8];
    const int count = end - start;
    if (count <= 0) return;

    const int rx = (int)compact1by2((uint32_t)reg);
    const int ry = (int)compact1by2((uint32_t)reg >> 1);
    const int rz = (int)compact1by2((uint32_t)reg >> 2);

    const int tid = threadIdx.x;
    load_tile<0>(ws, tile, rx, ry, rz, tid);
    load_tile<1>(ws, tile, rx, ry, rz, tid);
    load_tile<2>(ws, tile, rx, ry, rz, tid);
    load_tile<3>(ws, tile, rx, ry, rz, tid);
    __syncthreads();

    const int w = tid >> 6;   // wave = level
    const int lane = tid & 63;  // lane = point slot

    const int iters = (count + 63) >> 6;
    for (int it = 0; it < iters; ++it) {
        const int s = start + it * 64 + lane;
        const f32x4 r4 = rec[min(s, end - 1)];
        const float cx = r4.x, cy = r4.y, cz = r4.z;

        float acc[16];
        if (w == 0) gather_level<0>(tile, rx, ry, rz, cx, cy, cz, acc);
        else if (w == 1) gather_level<1>(tile, rx, ry, rz, cx, cy, cz, acc);
        else if (w == 2) gather_level<2>(tile, rx, ry, rz, cx, cy, cz, acc);
        else gather_level<3>(tile, rx, ry, rz, cx, cy, cz, acc);

        // stage: row = point(lane), cols w*16.. ; XOR swizzle for bank balance
        float* srow = &sacc[lane * 64];
#pragma unroll
        for (int j = 0; j < 4; ++j) {
            f32x4 v = {acc[4 * j + 0] * GRID_INV_SCALE, acc[4 * j + 1] * GRID_INV_SCALE,
                       acc[4 * j + 2] * GRID_INV_SCALE, acc[4 * j + 3] * GRID_INV_SCALE};
            *reinterpret_cast<f32x4*>(&srow[((w * 16 + j * 4) ^ ((lane & 7) << 3))]) = v;
        }
        if (w == 0) sp[lane] = __float_as_int(r4.w);
        __syncthreads();

        // scatter: wave w handles points w*16..w*16+15; 16 lanes x 16 B per point
#pragma unroll
        for (int gq = 0; gq < 4; ++gq) {
            const int i2 = w * 16 + gq * 4 + (lane >> 4);
            const int s2 = start + it * 64 + i2;
            if (s2 < end) {
                const int p = sp[i2];
                const int c4 = lane & 15;
                f32x4 v = *reinterpret_cast<const f32x4*>(
                    &sacc[i2 * 64 + ((c4 * 4) ^ ((i2 & 7) << 3))]);
                __builtin_nontemporal_store(
                    v, reinterpret_cast<f32x4*>(out + (size_t)p * 64 + c4 * 4));
            }
        }
        __syncthreads();
    }
}

// ---- fallback (no ws): direct strided f32 gather, slow but correct ----
__global__ void __launch_bounds__(256)
decomp_direct_kernel(const float* __restrict__ x, const float* __restrict__ g0,
                     const float* __restrict__ g1, const float* __restrict__ g2,
                     const float* __restrict__ g3, float* __restrict__ out, int n) {
    int p = blockIdx.x * blockDim.x + threadIdx.x;
    if (p >= n) return;
    const float cx = x[3 * (size_t)p], cy = x[3 * (size_t)p + 1], cz = x[3 * (size_t)p + 2];
    const float* grids[4] = {g0, g1, g2, g3};
#pragma unroll
    for (int l = 0; l < 4; ++l) {
        const int R = level_res(l);
        const float* g = grids[l];
        float fx = (cx + 1.0f) * 0.5f * (R - 1), fy = (cy + 1.0f) * 0.5f * (R - 1),
              fz = (cz + 1.0f) * 0.5f * (R - 1);
        int x0 = min(max((int)floorf(fx), 0), R - 2);
        int y0 = min(max((int)floorf(fy), 0), R - 2);
        int z0 = min(max((int)floorf(fz), 0), R - 2);
        float wx = fx - x0, wy = fy - y0, wz = fz - z0;
        const size_t V = (size_t)R * R * R;
        const int base = (z0 * R + y0) * R + x0;
        const int ro[4] = {0, R, R * R, R * R + R};
        const float wzy[4] = {(1 - wz) * (1 - wy), (1 - wz) * wy, wz * (1 - wy), wz * wy};
        for (int c = 0; c < 16; ++c) {
            float a = 0.f;
            for (int k = 0; k < 4; ++k) {
                const float* gc = g + (size_t)c * V + base + ro[k];
                a += wzy[k] * ((1 - wx) * gc[0] + wx * gc[1]);
            }
            out[(size_t)p * 64 + l * 16 + c] = a;
        }
    }
}

extern "C" void kernel_launch(void* const* d_in, const int* in_sizes, int n_in,
                              void* d_out, int out_size, void* d_ws, size_t ws_size,
                              hipStream_t stream) {
    const float* x = (const float*)d_in[0];
    const float* g[4] = {(const float*)d_in[1], (const float*)d_in[2],
                         (const float*)d_in[3], (const float*)d_in[4]};
    float* out = (float*)d_out;
    const int n = in_sizes[0] / 3;

    // ws layout: [grids fp16 76,677,120 B][rec 16n][hist][offs][bin_start]
    size_t grid_halfs = 0;
    for (int l = 0; l < 4; ++l) {
        size_t R = (size_t)level_res(l);
        grid_halfs += R * R * R * 16;
    }
    const size_t grid_bytes = grid_halfs * sizeof(__half);
    const size_t rec_off = grid_bytes;
    const size_t hist_off = rec_off + (size_t)n * 16;
    const size_t offs_off = hist_off + (size_t)NBINS * 4;
    const size_t bstart_off = offs_off + (size_t)NBINS * 4;
    const size_t needed = bstart_off + (size_t)(NBINS + 1) * 4;

    const int block = 256;
    if (ws_size < needed) {
        int grid = (n + block - 1) / block;
        decomp_direct_kernel<<<grid, block, 0, stream>>>(x, g[0], g[1], g[2], g[3], out, n);
        return;
    }

    char* wsb = (char*)d_ws;
    __half* wsh = (__half*)d_ws;
    f32x4* rec = (f32x4*)(wsb + rec_off);
    int* hist = (int*)(wsb + hist_off);
    int* offs = (int*)(wsb + offs_off);
    int* bstart = (int*)(wsb + bstart_off);

    const int total_vox = 4096 + 32768 + 262144 + 2097152;
    transpose_all_kernel<<<(total_vox + block - 1) / block, block, 0, stream>>>(
        g[0], g[1], g[2], g[3], wsh, total_vox);

    hipMemsetAsync(hist, 0, (size_t)NBINS * 4, stream);
    int pgrid = (n + block - 1) / block;
    hist_kernel<<<pgrid, block, 0, stream>>>(x, hist, n);
    scan_kernel<<<1, 1024, 0, stream>>>(hist, offs, bstart);
    scatter_rec_kernel<<<pgrid, block, 0, stream>>>(x, offs, rec, n);

    decomp_region_kernel<<<NREG, block, 0, stream>>>(rec, wsh, bstart, out);
}